// Round 1
// baseline (228.932 us; speedup 1.0000x reference)
//
#include <hip/hip_runtime.h>
#include <cmath>

#define BB 8
#define CC 64
#define HH 128
#define WW 128

typedef short s8v __attribute__((ext_vector_type(8)));      // raw 16B move
typedef float f4v __attribute__((ext_vector_type(4)));      // 4 fp32 acc
typedef _Float16 h8 __attribute__((ext_vector_type(8)));    // 8 f16 (4 VGPRs)
typedef unsigned short u16;
typedef u16 u4v __attribute__((ext_vector_type(4)));

__device__ __forceinline__ u16 f2h(float f) {
    _Float16 h = (_Float16)f;
    return __builtin_bit_cast(u16, h);
}
__device__ __forceinline__ _Float16 h_from_bits(u16 b) {
    return __builtin_bit_cast(_Float16, b);
}

// ---------------------------------------------------------------------------
// Kernel 0: NCHW fp32 (x_vq ++ x_res) -> NHWC f16 xin[B][H][W][128]
// float4 global reads, LDS transpose, ushort4 coalesced writes.
// ---------------------------------------------------------------------------
__global__ __launch_bounds__(256)
void x2nhwc_kernel(const float* __restrict__ xvq, const float* __restrict__ xres,
                   u16* __restrict__ xout)
{
    const int h = blockIdx.x;
    const int b = blockIdx.y;
    __shared__ u16 lds[128 * 132];

    for (int i = 0; i < 16; ++i) {
        const int idx = threadIdx.x + 256 * i;       // 4096 float4
        const int c = idx >> 5;
        const int w4 = (idx & 31) * 4;
        const float* src = (c < 64)
            ? &xvq[(((size_t)b * 64 + c) * HH + h) * WW]
            : &xres[(((size_t)b * 64 + (c - 64)) * HH + h) * WW];
        const float4 v = *(const float4*)(src + w4);
        lds[(w4 + 0) * 132 + c] = f2h(v.x);
        lds[(w4 + 1) * 132 + c] = f2h(v.y);
        lds[(w4 + 2) * 132 + c] = f2h(v.z);
        lds[(w4 + 3) * 132 + c] = f2h(v.w);
    }
    __syncthreads();
    u16* orow = xout + (((size_t)b * HH + h) * WW) * 128;
    for (int i = 0; i < 16; ++i) {
        const int idx = threadIdx.x + 256 * i;       // 4096 ushort4
        const int w = idx >> 5;
        const int q = idx & 31;
        *(u4v*)(orow + (size_t)w * 128 + q * 4) = *(const u4v*)&lds[w * 132 + q * 4];
    }
}

// ---------------------------------------------------------------------------
// Fused weight transforms (fp32 -> f16):
//  W1  [oc64][ic128][3][3] -> W1t  [tap9][oc64][ic128]     (73728)
//  Woff[18]/Wmod[9]        -> Womt [tap9][o32(27)][c64]    (18432)
//  Wdcn[oc][c][k]          -> Wdt  [k9][oc64][c64]         (36864)
// ---------------------------------------------------------------------------
__global__ void wfuse_kernel(const float* __restrict__ W1, const float* __restrict__ Woff,
                             const float* __restrict__ Wmod, const float* __restrict__ Wdcn,
                             u16* __restrict__ W1t, u16* __restrict__ Womt,
                             u16* __restrict__ Wdt)
{
    int idx = blockIdx.x * 256 + threadIdx.x;
    if (idx < 73728) {
        const int ic = idx & 127;
        const int oc = (idx >> 7) & 63;
        const int t  = idx >> 13;
        W1t[idx] = f2h(W1[((size_t)(oc * 128 + ic)) * 9 + t]);
        return;
    }
    idx -= 73728;
    if (idx < 18432) {
        const int c = idx & 63;
        const int o = (idx >> 6) & 31;
        const int t = idx >> 11;
        float v = 0.f;
        if (o < 18)      v = Woff[((size_t)(o * 64 + c)) * 9 + t];
        else if (o < 27) v = Wmod[((size_t)((o - 18) * 64 + c)) * 9 + t];
        Womt[idx] = f2h(v);
        return;
    }
    idx -= 18432;
    if (idx < 36864) {
        const int c  = idx & 63;
        const int oc = (idx >> 6) & 63;
        const int k  = idx >> 12;
        Wdt[idx] = f2h(Wdcn[((size_t)(oc * 64 + c)) * 9 + k]);
    }
}

// ---------------------------------------------------------------------------
// Kernel A: conv1 implicit-GEMM f16 MFMA. 16x16 px x 64 oc per block.
// K chunked by 32 ic; all 9 taps' weights for the chunk resident in LDS.
// feat out: f16 NHWC [B][H][W][64].
// ---------------------------------------------------------------------------
__global__ __launch_bounds__(256)
void conv1_mfma_kernel(const u16* __restrict__ xin, const u16* __restrict__ W1t,
                       const float* __restrict__ b1, u16* __restrict__ feath)
{
    __shared__ u16 sTile[324 * 36];   // [18x18][ic32 pad36] 23.3 KB
    __shared__ u16 sW[576 * 36];      // [tap*64+oc][ic32 pad36] 41.5 KB

    const int x0 = blockIdx.x * 16;
    const int y0 = blockIdx.y * 16;
    const int b  = blockIdx.z;
    const int tid = threadIdx.x;
    const int lane = tid & 63;
    const int wave = tid >> 6;
    const int lm = lane & 15;
    const int kg = lane >> 4;

    const u16* xb = xin + ((size_t)b * HH * WW) * 128;

    f4v acc[4][4];
#pragma unroll
    for (int i = 0; i < 4; ++i)
#pragma unroll
        for (int j = 0; j < 4; ++j) acc[i][j] = (f4v)0.f;

    for (int chunk = 0; chunk < 4; ++chunk) {
        const int c0 = chunk * 32;
        __syncthreads();
        for (int i = 0; i < 6; ++i) {
            const int idx = tid + 256 * i;
            if (idx < 1296) {
                const int pix = idx >> 2;
                const int q   = idx & 3;
                const int gy = y0 - 1 + pix / 18;
                const int gx = x0 - 1 + pix % 18;
                s8v v = (s8v)0;
                if ((unsigned)gy < HH && (unsigned)gx < WW)
                    v = *(const s8v*)(xb + ((size_t)(gy * WW + gx)) * 128 + c0 + q * 8);
                *(s8v*)&sTile[pix * 36 + q * 8] = v;
            }
        }
        for (int i = 0; i < 9; ++i) {
            const int idx = tid + 256 * i;
            const int row = idx >> 2;      // t*64 + oc
            const int q   = idx & 3;
            *(s8v*)&sW[row * 36 + q * 8] =
                *(const s8v*)(W1t + (size_t)row * 128 + c0 + q * 8);
        }
        __syncthreads();

#pragma unroll
        for (int t = 0; t < 9; ++t) {
            const int dy = t / 3, dx = t % 3;
            h8 a[4], bq[4];
#pragma unroll
            for (int mt = 0; mt < 4; ++mt) {
                const int p = wave * 64 + mt * 16 + lm;
                const int sidx = ((p >> 4) + dy) * 18 + (p & 15) + dx;
                a[mt] = *(const h8*)&sTile[sidx * 36 + kg * 8];
            }
#pragma unroll
            for (int nt = 0; nt < 4; ++nt) {
                const int oc = nt * 16 + lm;
                bq[nt] = *(const h8*)&sW[(t * 64 + oc) * 36 + kg * 8];
            }
#pragma unroll
            for (int mt = 0; mt < 4; ++mt)
#pragma unroll
                for (int nt = 0; nt < 4; ++nt)
                    acc[mt][nt] = __builtin_amdgcn_mfma_f32_16x16x32_f16(
                        a[mt], bq[nt], acc[mt][nt], 0, 0, 0);
        }
    }

#pragma unroll
    for (int nt = 0; nt < 4; ++nt) {
        const int oc = nt * 16 + lm;
        const float bias = b1[oc];
#pragma unroll
        for (int mt = 0; mt < 4; ++mt)
#pragma unroll
            for (int r = 0; r < 4; ++r) {
                const int p = wave * 64 + mt * 16 + kg * 4 + r;
                const int y = y0 + (p >> 4), x = x0 + (p & 15);
                feath[(((size_t)b * HH + y) * WW + x) * CC + oc] =
                    f2h(acc[mt][nt][r] + bias);
            }
    }
}

// ---------------------------------------------------------------------------
// Kernel B: offset+mod conv, 16x16 px x 32(27) out per block, f16 MFMA.
// ---------------------------------------------------------------------------
__global__ __launch_bounds__(256)
void offmod_mfma_kernel(const u16* __restrict__ feath, const u16* __restrict__ Womt,
                        const float* __restrict__ boff, const float* __restrict__ bmod,
                        float* __restrict__ om)
{
    __shared__ u16 sTile[324 * 36];   // [18x18][c32 pad36] 23.3 KB
    __shared__ u16 sWom[288 * 36];    // [t*32+o][c32 pad36] 20.7 KB

    const int x0 = blockIdx.x * 16;
    const int y0 = blockIdx.y * 16;
    const int b  = blockIdx.z;
    const int tid = threadIdx.x;
    const int lane = tid & 63;
    const int wave = tid >> 6;
    const int lm = lane & 15;
    const int kg = lane >> 4;

    const u16* fb = feath + ((size_t)b * HH * WW) * CC;

    f4v acc[4][2];
#pragma unroll
    for (int i = 0; i < 4; ++i)
#pragma unroll
        for (int j = 0; j < 2; ++j) acc[i][j] = (f4v)0.f;

    for (int chunk = 0; chunk < 2; ++chunk) {
        const int c0 = chunk * 32;
        __syncthreads();
        for (int i = 0; i < 6; ++i) {
            const int idx = tid + 256 * i;
            if (idx < 1296) {
                const int pix = idx >> 2;
                const int q   = idx & 3;
                const int gy = y0 - 1 + pix / 18;
                const int gx = x0 - 1 + pix % 18;
                s8v v = (s8v)0;
                if ((unsigned)gy < HH && (unsigned)gx < WW)
                    v = *(const s8v*)(fb + ((size_t)(gy * WW + gx)) * CC + c0 + q * 8);
                *(s8v*)&sTile[pix * 36 + q * 8] = v;
            }
        }
        for (int i = 0; i < 5; ++i) {
            const int idx = tid + 256 * i;
            if (idx < 1152) {
                const int row = idx >> 2;     // t*32 + o
                const int q   = idx & 3;
                *(s8v*)&sWom[row * 36 + q * 8] =
                    *(const s8v*)(Womt + (size_t)row * 64 + c0 + q * 8);
            }
        }
        __syncthreads();

#pragma unroll
        for (int t = 0; t < 9; ++t) {
            const int dy = t / 3, dx = t % 3;
            h8 a[4], bq[2];
#pragma unroll
            for (int mt = 0; mt < 4; ++mt) {
                const int p = wave * 64 + mt * 16 + lm;
                const int sidx = ((p >> 4) + dy) * 18 + (p & 15) + dx;
                a[mt] = *(const h8*)&sTile[sidx * 36 + kg * 8];
            }
#pragma unroll
            for (int nt = 0; nt < 2; ++nt) {
                const int o = nt * 16 + lm;
                bq[nt] = *(const h8*)&sWom[(t * 32 + o) * 36 + kg * 8];
            }
#pragma unroll
            for (int mt = 0; mt < 4; ++mt)
#pragma unroll
                for (int nt = 0; nt < 2; ++nt)
                    acc[mt][nt] = __builtin_amdgcn_mfma_f32_16x16x32_f16(
                        a[mt], bq[nt], acc[mt][nt], 0, 0, 0);
        }
    }

#pragma unroll
    for (int nt = 0; nt < 2; ++nt) {
        const int o = nt * 16 + lm;
        if (o >= 27) continue;
#pragma unroll
        for (int mt = 0; mt < 4; ++mt)
#pragma unroll
            for (int r = 0; r < 4; ++r) {
                const int p = wave * 64 + mt * 16 + kg * 4 + r;
                const int y = y0 + (p >> 4), x = x0 + (p & 15);
                float* op = om + (((size_t)b * HH + y) * WW + x) * 27;
                if (o < 18) op[o] = acc[mt][nt][r] + boff[o];
                else {
                    const float z = acc[mt][nt][r] + bmod[o - 18];
                    op[o] = 2.f / (1.f + expf(-z));
                }
            }
    }
}

// ---------------------------------------------------------------------------
// Kernel C: deformable sampling + modulated einsum, f16.
// Rework vs previous version (latency/barrier-bound: MfmaUtil 8%, VALUBusy 25%,
// HBM 15%, occupancy 30% with 39.4KB LDS):
//  - bilinear records computed inline per thread (no sOffs/sWts LDS stage)
//  - Wd B-fragments loaded straight from global (L2-resident 144KB table)
//  - sV double-buffered -> ONE barrier per tap instead of two
//  - gather for tap k+1 issued BEFORE the barrier (T14 split): L2 latency
//    hides under tap-k MFMA (separate pipes).
// LDS: 2*9.2KB (sV) + 7.2KB (sOm) = 25.6KB -> up to 6 blocks/CU.
// ---------------------------------------------------------------------------
__global__ __launch_bounds__(256, 4)
void dcn_mfma_kernel(const u16* __restrict__ feath, const float* __restrict__ om,
                     const u16* __restrict__ Wdt, const float* __restrict__ bdcn,
                     float* __restrict__ out)
{
    __shared__ u16 sV[2][64 * 72];    // [buf][p][c64 pad72] 2 x 9.2 KB
    __shared__ float sOm[64 * 28];    // [p][27 pad28] 7.2 KB

    const int b  = blockIdx.z;
    const int x0 = blockIdx.x * 8;
    const int y0 = blockIdx.y * 8;
    const int tid = threadIdx.x;
    const int lane = tid & 63;
    const int wave = tid >> 6;
    const int wi = wave >> 1;
    const int wj = wave & 1;
    const int lm = lane & 15;
    const int kg = lane >> 4;

    for (int idx = tid; idx < 64 * 27; idx += 256) {
        const int p = idx / 27;
        const int j = idx - p * 27;
        const int y = y0 + (p >> 3), x = x0 + (p & 7);
        sOm[p * 28 + j] = om[(((size_t)b * HH + y) * WW + x) * 27 + j];
    }
    __syncthreads();

    // gather mapping: thread = (pixel p1, 16-ch group)
    const int p1 = tid >> 2;
    const int cb = (tid & 3) * 16;
    const int yy = y0 + (p1 >> 3);
    const int xx = x0 + (p1 & 7);

    const u16* fb = feath + ((size_t)b * HH * WW) * CC;

    // inline bilinear record + gather for one tap (redundant x4 across cb,
    // but removes the LDS record stage and its barrier dependency)
    auto gather_tap = [&](int k, h8& r0, h8& r1) {
        const float dy = sOm[p1 * 28 + 2 * k];
        const float dx = sOm[p1 * 28 + 2 * k + 1];
        const float m  = sOm[p1 * 28 + 18 + k];
        const float pyf = (float)(yy + (k / 3) - 1) + dy;
        const float pxf = (float)(xx + (k % 3) - 1) + dx;
        const float fy0 = floorf(pyf), fx0 = floorf(pxf);
        const float wy1 = pyf - fy0, wx1 = pxf - fx0;
        const int iy0 = (int)fy0, ix0 = (int)fx0;
        const float wq[4] = { m * (1.f - wy1) * (1.f - wx1), m * (1.f - wy1) * wx1,
                              m * wy1 * (1.f - wx1),         m * wy1 * wx1 };
        const int ys[4] = { iy0, iy0, iy0 + 1, iy0 + 1 };
        const int xs[4] = { ix0, ix0 + 1, ix0, ix0 + 1 };
        h8 a0 = (h8)(_Float16)0.f, a1 = (h8)(_Float16)0.f;
#pragma unroll
        for (int cn = 0; cn < 4; ++cn) {
            const bool valid = ((unsigned)ys[cn] < (unsigned)HH) &&
                               ((unsigned)xs[cn] < (unsigned)WW);
            const int off = valid ? (ys[cn] * WW + xs[cn]) * CC : 0;
            const h8 w8 = (h8)(_Float16)(valid ? wq[cn] : 0.f);
            const u16* cp = fb + off + cb;
            a0 += w8 * *(const h8*)(cp);
            a1 += w8 * *(const h8*)(cp + 8);
        }
        r0 = a0;
        r1 = a1;
    };

    f4v acc[2][2];
#pragma unroll
    for (int i = 0; i < 2; ++i)
#pragma unroll
        for (int j = 0; j < 2; ++j) acc[i][j] = (f4v)0.f;

    h8 g0, g1;
    gather_tap(0, g0, g1);

    for (int k = 0; k < 9; ++k) {
        // publish tap-k V into the current buffer
        u16* vd = &sV[k & 1][p1 * 72 + cb];
        *(h8*)vd       = g0;
        *(h8*)(vd + 8) = g1;

        // B-fragments for tap k straight from global (144KB table, L2-hot)
        h8 bf[2][2];
        const u16* wp = Wdt + ((size_t)k * 64 + wj * 32 + lm) * 64 + kg * 8;
#pragma unroll
        for (int nt = 0; nt < 2; ++nt)
#pragma unroll
            for (int ks = 0; ks < 2; ++ks)
                bf[nt][ks] = *(const h8*)(wp + nt * 16 * 64 + ks * 32);

        // issue next tap's gather BEFORE the barrier: L2 latency hides
        // under this tap's MFMA
        h8 n0 = (h8)(_Float16)0.f, n1 = (h8)(_Float16)0.f;
        if (k < 8) gather_tap(k + 1, n0, n1);

        __syncthreads();   // writes to buf[k&1] visible; separates reads(k-1)
                           // of buf[(k-1)&1] from writes(k+1)

        // ---- GEMM: acc += V[64p][64c] * Wd[64c][64oc] ----
        h8 a[2][2];
#pragma unroll
        for (int mt = 0; mt < 2; ++mt) {
            const int p = wi * 32 + mt * 16 + lm;
#pragma unroll
            for (int ks = 0; ks < 2; ++ks)
                a[mt][ks] = *(const h8*)&sV[k & 1][p * 72 + ks * 32 + kg * 8];
        }
#pragma unroll
        for (int mt = 0; mt < 2; ++mt)
#pragma unroll
            for (int nt = 0; nt < 2; ++nt)
#pragma unroll
                for (int ks = 0; ks < 2; ++ks)
                    acc[mt][nt] = __builtin_amdgcn_mfma_f32_16x16x32_f16(
                        a[mt][ks], bf[nt][ks], acc[mt][nt], 0, 0, 0);

        g0 = n0;
        g1 = n1;
    }

    // epilogue: NCHW fp32
#pragma unroll
    for (int mt = 0; mt < 2; ++mt)
#pragma unroll
        for (int nt = 0; nt < 2; ++nt) {
            const int oc = wj * 32 + nt * 16 + lm;
            const float bias = bdcn[oc];
#pragma unroll
            for (int r = 0; r < 4; ++r) {
                const int p = wi * 32 + mt * 16 + kg * 4 + r;
                const int y = y0 + (p >> 3), x = x0 + (p & 7);
                out[(((size_t)b * CC + oc) * HH + y) * WW + x] = acc[mt][nt][r] + bias;
            }
        }
}

extern "C" void kernel_launch(void* const* d_in, const int* in_sizes, int n_in,
                              void* d_out, int out_size, void* d_ws, size_t ws_size,
                              hipStream_t stream)
{
    const float* xvq  = (const float*)d_in[0];
    const float* xres = (const float*)d_in[1];
    const float* W1   = (const float*)d_in[2];
    const float* b1   = (const float*)d_in[3];
    const float* Woff = (const float*)d_in[4];
    const float* boff = (const float*)d_in[5];
    const float* Wmod = (const float*)d_in[6];
    const float* bmod = (const float*)d_in[7];
    const float* Wdcn = (const float*)d_in[8];
    const float* bdcn = (const float*)d_in[9];
    float* out = (float*)d_out;

    u16*  feath = (u16*)d_ws;                              // 8.39M u16
    float* om   = (float*)(feath + (size_t)BB * HH * WW * CC);  // 3.54M f32
    u16*  xin   = (u16*)(om + (size_t)BB * HH * WW * 27);  // 16.78M u16
    u16*  W1t   = xin + (size_t)BB * HH * WW * 128;        // 73728 u16
    u16*  Womt  = W1t + 9 * 64 * 128;                      // 18432 u16
    u16*  Wdt   = Womt + 9 * 32 * 64;                      // 36864 u16

    x2nhwc_kernel<<<dim3(HH, BB), 256, 0, stream>>>(xvq, xres, xin);
    wfuse_kernel<<<dim3(504), 256, 0, stream>>>(W1, Woff, Wmod, Wdcn, W1t, Womt, Wdt);
    conv1_mfma_kernel<<<dim3(8, 8, 8), 256, 0, stream>>>(xin, W1t, b1, feath);
    offmod_mfma_kernel<<<dim3(8, 8, 8), 256, 0, stream>>>(feath, Womt, boff, bmod, om);
    dcn_mfma_kernel<<<dim3(16, 16, 8), 256, 0, stream>>>(feath, om, Wdt, bdcn, out);
}